// Round 1
// baseline (1738.659 us; speedup 1.0000x reference)
//
#include <hip/hip_runtime.h>

// EGNN forward, f32 baseline.
// ws layout (floats): h[N*64] | agg_m[N*64] | agg_x[N*3] | cnt[N]
// d_out layout (floats): out[N*64] | coords_out[N*3]

__device__ __forceinline__ void atomAddF(float* p, float v) {
  unsafeAtomicAdd(p, v);  // HW global_atomic_add_f32 on gfx950
}

// ---------------- Kernel 1: h = node_feats @ W_in + b_in ----------------
__global__ __launch_bounds__(256) void k_embed(
    const float* __restrict__ nf, const float* __restrict__ W_in,
    const float* __restrict__ b_in, float* __restrict__ h, int N) {
  __shared__ float Ws[32 * 64];
  for (int i = threadIdx.x; i < 32 * 64; i += 256) Ws[i] = W_in[i];
  __syncthreads();
  const int wave = threadIdx.x >> 6, lane = threadIdx.x & 63;
  const float bv = b_in[lane];
  const int nwaves = gridDim.x * 4;
  for (int n = blockIdx.x * 4 + wave; n < N; n += nwaves) {
    float v = (lane < 32) ? nf[(size_t)n * 32 + lane] : 0.0f;
    float acc = bv;
#pragma unroll
    for (int k = 0; k < 32; ++k)
      acc = fmaf(__shfl(v, k, 64), Ws[k * 64 + lane], acc);
    h[(size_t)n * 64 + lane] = acc;
  }
}

// ---------------- Kernel 2: edge MLP + fused atomic aggregation ----------
// x layout per edge (stride 148): [0:64) h_row | [64:128) h_col | [128] radial
// | [129:145) edge_attr | [145:148) coord_diff
__global__ __launch_bounds__(256) void k_edge(
    const float* __restrict__ h, const float* __restrict__ ea,
    const float* __restrict__ co, const int* __restrict__ eidx,
    const float* __restrict__ We1, const float* __restrict__ be1,
    const float* __restrict__ We2, const float* __restrict__ be2,
    const float* __restrict__ Wc1, const float* __restrict__ bc1,
    const float* __restrict__ Wc2, const float* __restrict__ bc2,
    float* __restrict__ agg_m, float* __restrict__ agg_x,
    float* __restrict__ cnt, int E) {
  __shared__ float We1s[145 * 64];
  __shared__ float We2s[64 * 64];
  __shared__ float Wc1s[64 * 64];
  __shared__ float Wc2s[64];
  __shared__ float be1s[64], be2s[64], bc1s[64];
  __shared__ float xls[4][4][148];  // [wave][edge][feat]

  for (int i = threadIdx.x; i < 145 * 64; i += 256) We1s[i] = We1[i];
  for (int i = threadIdx.x; i < 64 * 64; i += 256) {
    We2s[i] = We2[i];
    Wc1s[i] = Wc1[i];
  }
  if (threadIdx.x < 64) {
    Wc2s[threadIdx.x] = Wc2[threadIdx.x];
    be1s[threadIdx.x] = be1[threadIdx.x];
    be2s[threadIdx.x] = be2[threadIdx.x];
    bc1s[threadIdx.x] = bc1[threadIdx.x];
  }
  __syncthreads();

  const int wave = threadIdx.x >> 6, lane = threadIdx.x & 63;
  const float bc2v = bc2[0];
  float(*xw)[148] = xls[wave];
  const int ngroups = (E + 3) >> 2;
  const int nwaves = gridDim.x * 4;

  for (int g = blockIdx.x * 4 + wave; g < ngroups; g += nwaves) {
    const int e0 = g << 2;
    int ne = E - e0;
    if (ne > 4) ne = 4;
    int r[4], c[4];
#pragma unroll
    for (int i = 0; i < 4; ++i) {
      const int e = e0 + ((i < ne) ? i : (ne - 1));  // clamp tail (stores guarded)
      r[i] = eidx[e];
      c[i] = eidx[E + e];
      xw[i][lane] = h[(size_t)r[i] * 64 + lane];
      xw[i][64 + lane] = h[(size_t)c[i] * 64 + lane];
      if (lane < 16) xw[i][129 + lane] = ea[(size_t)e * 16 + lane];
      if (lane < 3) xw[i][145 + lane] = co[(size_t)r[i] * 3 + lane] - co[(size_t)c[i] * 3 + lane];
      if (lane == 0) {
        // wave-local LDS: same-wave write->read, compiler inserts lgkmcnt
      }
    }
    if (lane == 0) {
#pragma unroll
      for (int i = 0; i < 4; ++i) {
        float dx = xw[i][145], dy = xw[i][146], dz = xw[i][147];
        xw[i][128] = dx * dx + dy * dy + dz * dz;
      }
    }

    // ---- layer 1: [4][145] @ [145][64] ----
    float a[4];
#pragma unroll
    for (int i = 0; i < 4; ++i) a[i] = be1s[lane];
    for (int kk = 0; kk < 36; ++kk) {
      const float w0 = We1s[(kk * 4 + 0) * 64 + lane];
      const float w1 = We1s[(kk * 4 + 1) * 64 + lane];
      const float w2 = We1s[(kk * 4 + 2) * 64 + lane];
      const float w3 = We1s[(kk * 4 + 3) * 64 + lane];
#pragma unroll
      for (int i = 0; i < 4; ++i) {
        const float4 xv = *reinterpret_cast<const float4*>(&xw[i][kk * 4]);
        a[i] = fmaf(xv.x, w0, a[i]);
        a[i] = fmaf(xv.y, w1, a[i]);
        a[i] = fmaf(xv.z, w2, a[i]);
        a[i] = fmaf(xv.w, w3, a[i]);
      }
    }
    {
      const float w = We1s[144 * 64 + lane];
#pragma unroll
      for (int i = 0; i < 4; ++i) a[i] = fmaf(xw[i][144], w, a[i]);
    }
#pragma unroll
    for (int i = 0; i < 4; ++i) {
      a[i] = fmaxf(a[i], 0.0f);
      xw[i][lane] = a[i];  // t1 -> x region [0:64)
    }

    // ---- layer 2: [4][64] @ [64][64] -> m ----
    float m[4];
#pragma unroll
    for (int i = 0; i < 4; ++i) m[i] = be2s[lane];
    for (int kk = 0; kk < 16; ++kk) {
      const float w0 = We2s[(kk * 4 + 0) * 64 + lane];
      const float w1 = We2s[(kk * 4 + 1) * 64 + lane];
      const float w2 = We2s[(kk * 4 + 2) * 64 + lane];
      const float w3 = We2s[(kk * 4 + 3) * 64 + lane];
#pragma unroll
      for (int i = 0; i < 4; ++i) {
        const float4 xv = *reinterpret_cast<const float4*>(&xw[i][kk * 4]);
        m[i] = fmaf(xv.x, w0, m[i]);
        m[i] = fmaf(xv.y, w1, m[i]);
        m[i] = fmaf(xv.z, w2, m[i]);
        m[i] = fmaf(xv.w, w3, m[i]);
      }
    }
#pragma unroll
    for (int i = 0; i < 4; ++i) {
      m[i] = fmaxf(m[i], 0.0f);
      xw[i][64 + lane] = m[i];  // m -> x region [64:128)
    }

    // ---- coord MLP: p = relu(m@Wc1+bc1); s = p.Wc2 + bc2 ----
    float p[4];
#pragma unroll
    for (int i = 0; i < 4; ++i) p[i] = bc1s[lane];
    for (int kk = 0; kk < 16; ++kk) {
      const float w0 = Wc1s[(kk * 4 + 0) * 64 + lane];
      const float w1 = Wc1s[(kk * 4 + 1) * 64 + lane];
      const float w2 = Wc1s[(kk * 4 + 2) * 64 + lane];
      const float w3 = Wc1s[(kk * 4 + 3) * 64 + lane];
#pragma unroll
      for (int i = 0; i < 4; ++i) {
        const float4 xv = *reinterpret_cast<const float4*>(&xw[i][64 + kk * 4]);
        p[i] = fmaf(xv.x, w0, p[i]);
        p[i] = fmaf(xv.y, w1, p[i]);
        p[i] = fmaf(xv.z, w2, p[i]);
        p[i] = fmaf(xv.w, w3, p[i]);
      }
    }
    float s[4];
#pragma unroll
    for (int i = 0; i < 4; ++i) s[i] = fmaxf(p[i], 0.0f) * Wc2s[lane];
#pragma unroll
    for (int off = 32; off >= 1; off >>= 1) {
#pragma unroll
      for (int i = 0; i < 4; ++i) s[i] += __shfl_xor(s[i], off, 64);
    }
#pragma unroll
    for (int i = 0; i < 4; ++i) s[i] += bc2v;

    // ---- aggregation (by row) ----
#pragma unroll
    for (int i = 0; i < 4; ++i) {
      if (i < ne) {
        atomAddF(&agg_m[(size_t)r[i] * 64 + lane], m[i]);
        if (lane < 3) {
          const float cd = xw[i][145 + lane];
          atomAddF(&agg_x[(size_t)r[i] * 3 + lane], cd * s[i]);
        }
        if (lane == 4) atomAddF(&cnt[r[i]], 1.0f);
      }
    }
  }
}

// ---------------- Kernel 3: node MLP + output + coord update -------------
__global__ __launch_bounds__(256) void k_node(
    const float* __restrict__ h, const float* __restrict__ agg_m,
    const float* __restrict__ agg_x, const float* __restrict__ cnt,
    const float* __restrict__ co,
    const float* __restrict__ Wn1, const float* __restrict__ bn1,
    const float* __restrict__ Wn2, const float* __restrict__ bn2,
    const float* __restrict__ Wo, const float* __restrict__ bo,
    float* __restrict__ out, float* __restrict__ co_out, int N) {
  __shared__ float Wn1s[128 * 64];
  __shared__ float Wn2s[64 * 64];
  __shared__ float Wos[64 * 64];
  __shared__ float bn1s[64], bn2s[64], bos[64];
  __shared__ float xls[4][136];

  for (int i = threadIdx.x; i < 128 * 64; i += 256) Wn1s[i] = Wn1[i];
  for (int i = threadIdx.x; i < 64 * 64; i += 256) {
    Wn2s[i] = Wn2[i];
    Wos[i] = Wo[i];
  }
  if (threadIdx.x < 64) {
    bn1s[threadIdx.x] = bn1[threadIdx.x];
    bn2s[threadIdx.x] = bn2[threadIdx.x];
    bos[threadIdx.x] = bo[threadIdx.x];
  }
  __syncthreads();

  const int wave = threadIdx.x >> 6, lane = threadIdx.x & 63;
  float* xw = xls[wave];
  const int nwaves = gridDim.x * 4;

  for (int n = blockIdx.x * 4 + wave; n < N; n += nwaves) {
    xw[lane] = h[(size_t)n * 64 + lane];
    xw[64 + lane] = agg_m[(size_t)n * 64 + lane];

    float a = bn1s[lane];
    for (int kk = 0; kk < 32; ++kk) {
      const float4 xv = *reinterpret_cast<const float4*>(&xw[kk * 4]);
      a = fmaf(xv.x, Wn1s[(kk * 4 + 0) * 64 + lane], a);
      a = fmaf(xv.y, Wn1s[(kk * 4 + 1) * 64 + lane], a);
      a = fmaf(xv.z, Wn1s[(kk * 4 + 2) * 64 + lane], a);
      a = fmaf(xv.w, Wn1s[(kk * 4 + 3) * 64 + lane], a);
    }
    a = fmaxf(a, 0.0f);
    xw[lane] = a;  // q

    float a2 = bn2s[lane];
    for (int kk = 0; kk < 16; ++kk) {
      const float4 xv = *reinterpret_cast<const float4*>(&xw[kk * 4]);
      a2 = fmaf(xv.x, Wn2s[(kk * 4 + 0) * 64 + lane], a2);
      a2 = fmaf(xv.y, Wn2s[(kk * 4 + 1) * 64 + lane], a2);
      a2 = fmaf(xv.z, Wn2s[(kk * 4 + 2) * 64 + lane], a2);
      a2 = fmaf(xv.w, Wn2s[(kk * 4 + 3) * 64 + lane], a2);
    }
    xw[64 + lane] = a2;  // h2 (no relu)

    float a3 = bos[lane];
    for (int kk = 0; kk < 16; ++kk) {
      const float4 xv = *reinterpret_cast<const float4*>(&xw[64 + kk * 4]);
      a3 = fmaf(xv.x, Wos[(kk * 4 + 0) * 64 + lane], a3);
      a3 = fmaf(xv.y, Wos[(kk * 4 + 1) * 64 + lane], a3);
      a3 = fmaf(xv.z, Wos[(kk * 4 + 2) * 64 + lane], a3);
      a3 = fmaf(xv.w, Wos[(kk * 4 + 3) * 64 + lane], a3);
    }
    out[(size_t)n * 64 + lane] = a3;

    if (lane < 3)
      co_out[(size_t)n * 3 + lane] =
          co[(size_t)n * 3 + lane] + agg_x[(size_t)n * 3 + lane] / fmaxf(cnt[n], 1.0f);
  }
}

extern "C" void kernel_launch(void* const* d_in, const int* in_sizes, int n_in,
                              void* d_out, int out_size, void* d_ws, size_t ws_size,
                              hipStream_t stream) {
  const float* nf = (const float*)d_in[0];
  const float* ea = (const float*)d_in[1];
  const float* co = (const float*)d_in[2];
  const int* ei = (const int*)d_in[3];
  const float* W_in = (const float*)d_in[4];
  const float* b_in = (const float*)d_in[5];
  const float* W_out = (const float*)d_in[6];
  const float* b_out = (const float*)d_in[7];
  const float* We1 = (const float*)d_in[8];
  const float* be1 = (const float*)d_in[9];
  const float* We2 = (const float*)d_in[10];
  const float* be2 = (const float*)d_in[11];
  const float* Wn1 = (const float*)d_in[12];
  const float* bn1 = (const float*)d_in[13];
  const float* Wn2 = (const float*)d_in[14];
  const float* bn2 = (const float*)d_in[15];
  const float* Wc1 = (const float*)d_in[16];
  const float* bc1 = (const float*)d_in[17];
  const float* Wc2 = (const float*)d_in[18];
  const float* bc2 = (const float*)d_in[19];

  const int N = in_sizes[0] / 32;
  const int E = in_sizes[1] / 16;

  float* ws = (float*)d_ws;
  float* h = ws;
  float* agg_m = ws + (size_t)N * 64;
  float* agg_x = agg_m + (size_t)N * 64;
  float* cntb = agg_x + (size_t)N * 3;
  float* outp = (float*)d_out;
  float* co_out = outp + (size_t)N * 64;

  // zero agg_m | agg_x | cnt (contiguous N*68 floats)
  hipMemsetAsync(agg_m, 0, (size_t)N * 68 * sizeof(float), stream);

  k_embed<<<2048, 256, 0, stream>>>(nf, W_in, b_in, h, N);
  k_edge<<<2048, 256, 0, stream>>>(h, ea, co, ei, We1, be1, We2, be2, Wc1, bc1,
                                   Wc2, bc2, agg_m, agg_x, cntb, E);
  k_node<<<2048, 256, 0, stream>>>(h, agg_m, agg_x, cntb, co, Wn1, bn1, Wn2,
                                   bn2, W_out, b_out, outp, co_out, N);
}

// Round 2
// 617.049 us; speedup vs baseline: 2.8177x; 2.8177x over previous
//
#include <hip/hip_runtime.h>

// EGNN forward — MFMA edge kernel + per-node algebraic precompute.
// ws (floats): h[N*64] | agg_m[N*64] | agg_x[N*3] | cnt[N] | WA[2048] | WB[2048] | bSum[64]
// d_out (floats): out[N*64] | coords_out[N*3]
// d_out is additionally used as scratch for gA/gB (bf16) between k_embed and
// k_edge: gA = ushort[N*64] at d_out, gB = ushort[N*64] after it (bytes
// [0, N*256) = float slots [0, N*64) — overwritten by k_node's final output).

typedef __attribute__((ext_vector_type(4))) float f32x4;
typedef __attribute__((ext_vector_type(8))) short short8;

__device__ __forceinline__ void atomAddF(float* p, float v) { unsafeAtomicAdd(p, v); }

__device__ __forceinline__ unsigned short f2bf(float f) {
  unsigned int u = __builtin_bit_cast(unsigned int, f);
  unsigned int r = (u + 0x7FFFu + ((u >> 16) & 1u)) >> 16;
  return (unsigned short)r;
}
__device__ __forceinline__ float bf2f(unsigned short s) {
  unsigned int v = ((unsigned int)s) << 16;
  return __builtin_bit_cast(float, v);
}
__device__ __forceinline__ float lo_bf(unsigned int u) {
  return __builtin_bit_cast(float, u << 16);
}
__device__ __forceinline__ float hi_bf(unsigned int u) {
  return __builtin_bit_cast(float, u & 0xFFFF0000u);
}

// ---------------- k_fold: fold W_in into We1's h-parts -------------------
// WA = W_in @ We1[0:64,:]   (32x64)
// WB = W_in @ We1[64:128,:] (32x64)
// bSum = b_in@We1[0:64] + b_in@We1[64:128] + be1   (64)
__global__ void k_fold(const float* __restrict__ W_in, const float* __restrict__ b_in,
                       const float* __restrict__ We1, const float* __restrict__ be1,
                       float* __restrict__ WA, float* __restrict__ WB,
                       float* __restrict__ bSum) {
  const int t = threadIdx.x;
  for (int idx = t; idx < 2048; idx += 256) {
    const int i = idx >> 6, n = idx & 63;
    float sa = 0.f, sb = 0.f;
    for (int h = 0; h < 64; ++h) {
      const float w = W_in[i * 64 + h];
      sa = fmaf(w, We1[h * 64 + n], sa);
      sb = fmaf(w, We1[(64 + h) * 64 + n], sb);
    }
    WA[idx] = sa;
    WB[idx] = sb;
  }
  if (t < 64) {
    float s = be1[t];
    for (int h = 0; h < 64; ++h)
      s = fmaf(b_in[h], We1[h * 64 + t] + We1[(64 + h) * 64 + t], s);
    bSum[t] = s;
  }
}

// ---------------- k_embed: h, gA = nf@WA, gB = nf@WB ---------------------
__global__ __launch_bounds__(256) void k_embed(
    const float* __restrict__ nf, const float* __restrict__ W_in,
    const float* __restrict__ b_in, const float* __restrict__ WA,
    const float* __restrict__ WB, float* __restrict__ h,
    unsigned short* __restrict__ gA, unsigned short* __restrict__ gB, int N) {
  __shared__ float Ws[3 * 2048];      // W_in | WA | WB (each [32][64] f32)
  __shared__ float nfl[4][8][36];     // per-wave staged nf, padded rows
  for (int i = threadIdx.x; i < 2048; i += 256) {
    Ws[i] = W_in[i];
    Ws[2048 + i] = WA[i];
    Ws[4096 + i] = WB[i];
  }
  __syncthreads();
  const int w = threadIdx.x >> 6, lane = threadIdx.x & 63;
  const float bv = b_in[lane];
  const int NG = (N + 7) >> 3;
  for (int ng = blockIdx.x * 4 + w; ng < NG; ng += gridDim.x * 4) {
    const int base = ng * 8;
    {
      const int nl = lane >> 3, ch = lane & 7;
      int n = base + nl;
      if (n >= N) n = N - 1;
      const f32x4 v = *reinterpret_cast<const f32x4*>(nf + (size_t)n * 32 + ch * 4);
      *reinterpret_cast<f32x4*>(&nfl[w][nl][ch * 4]) = v;
    }
    float ah[8], aa[8], ab[8];
#pragma unroll
    for (int i = 0; i < 8; ++i) { ah[i] = bv; aa[i] = 0.f; ab[i] = 0.f; }
    for (int k4 = 0; k4 < 8; ++k4) {
      float w0[3][4];
#pragma unroll
      for (int q = 0; q < 4; ++q) {
        w0[0][q] = Ws[(k4 * 4 + q) * 64 + lane];
        w0[1][q] = Ws[2048 + (k4 * 4 + q) * 64 + lane];
        w0[2][q] = Ws[4096 + (k4 * 4 + q) * 64 + lane];
      }
#pragma unroll
      for (int i = 0; i < 8; ++i) {
        const f32x4 x = *reinterpret_cast<const f32x4*>(&nfl[w][i][k4 * 4]);
#pragma unroll
        for (int q = 0; q < 4; ++q) {
          ah[i] = fmaf(x[q], w0[0][q], ah[i]);
          aa[i] = fmaf(x[q], w0[1][q], aa[i]);
          ab[i] = fmaf(x[q], w0[2][q], ab[i]);
        }
      }
    }
#pragma unroll
    for (int i = 0; i < 8; ++i) {
      const int n = base + i;
      if (n < N) {
        h[(size_t)n * 64 + lane] = ah[i];
        gA[(size_t)n * 64 + lane] = f2bf(aa[i]);
        gB[(size_t)n * 64 + lane] = f2bf(ab[i]);
      }
    }
  }
}

// ---------------- k_edge: MFMA edge MLP + fused aggregation --------------
struct EdgeLds {
  unsigned short We2t[64 * 72];  // [n][k] bf16, padded k-stride 72
  unsigned short Wc1t[64 * 72];
  unsigned short Bea[64 * 40];   // [n][k] k<32: rows 0..15=ea wt, 16=radial wt
  float bSs[64], be2s[64], bc1s[64], wc2s[64];
  unsigned short x[4][32 * 72];  // per-wave: staged gA+gB sum -> t1 -> m (bf16)
  float cd[4][32 * 4];           // per-wave: dx,dy,dz,radial
  int idx[4][64];                // per-wave: r[32] | c[32]
};

__global__ __launch_bounds__(256, 2) void k_edge(
    const unsigned short* __restrict__ gA, const unsigned short* __restrict__ gB,
    const float* __restrict__ ea, const float* __restrict__ co,
    const int* __restrict__ eidx, const float* __restrict__ We1,
    const float* __restrict__ bSum, const float* __restrict__ be2,
    const float* __restrict__ We2, const float* __restrict__ bc1,
    const float* __restrict__ Wc1, const float* __restrict__ Wc2,
    const float* __restrict__ bc2, float* __restrict__ agg_m,
    float* __restrict__ agg_x, float* __restrict__ cnt, int E) {
  __shared__ EdgeLds S;
  const int tid = threadIdx.x;
  for (int i = tid; i < 4096; i += 256) {
    const int k = i >> 6, n = i & 63;
    S.We2t[n * 72 + k] = f2bf(We2[k * 64 + n]);
    S.Wc1t[n * 72 + k] = f2bf(Wc1[k * 64 + n]);
  }
  for (int i = tid; i < 2048; i += 256) {
    const int k = i >> 6, n = i & 63;  // k in 0..31
    const float v = (k < 16) ? We1[(129 + k) * 64 + n]
                             : ((k == 16) ? We1[128 * 64 + n] : 0.f);
    S.Bea[n * 40 + k] = f2bf(v);
  }
  if (tid < 64) {
    S.bSs[tid] = bSum[tid];
    S.be2s[tid] = be2[tid];
    S.bc1s[tid] = bc1[tid];
    S.wc2s[tid] = Wc2[tid];
  }
  __syncthreads();

  const int w = tid >> 6, lane = tid & 63;
  const int g = lane >> 4, t = lane & 15;
  const float bc2v = bc2[0];

  // persistent B-fragments: We2 only (Wc1/Bea re-read per group to save VGPRs)
  short8 fWe2[4][2];
  float bS_r[4], be2_r[4], bc1_r[4], wc2_r[4];
#pragma unroll
  for (int nt = 0; nt < 4; ++nt) {
    const int n = t + 16 * nt;
#pragma unroll
    for (int kt = 0; kt < 2; ++kt)
      fWe2[nt][kt] = *reinterpret_cast<const short8*>(&S.We2t[n * 72 + kt * 32 + g * 8]);
    bS_r[nt] = S.bSs[n];
    be2_r[nt] = S.be2s[n];
    bc1_r[nt] = S.bc1s[n];
    wc2_r[nt] = S.wc2s[n];
  }

  unsigned short* xw = &S.x[w][0];
  float* cdw = &S.cd[w][0];
  int* idxw = &S.idx[w][0];
  const int ngroups = (E + 31) >> 5;

  for (int grp = blockIdx.x * 4 + w; grp < ngroups; grp += gridDim.x * 4) {
    const long e0 = (long)grp * 32;
    // --- 1. edge indices ---
    {
      long e = e0 + (lane & 31);
      if (e >= E) e = E - 1;
      const int v = (lane < 32) ? eidx[e] : eidx[(long)E + e];
      idxw[(lane >> 5) * 32 + (lane & 31)] = v;
    }
    // --- 2. coord diff + radial (lanes 0..31) ---
    if (lane < 32) {
      const int rI = idxw[lane];
      const int cI = idxw[32 + lane];
      const float dx = co[(size_t)rI * 3 + 0] - co[(size_t)cI * 3 + 0];
      const float dy = co[(size_t)rI * 3 + 1] - co[(size_t)cI * 3 + 1];
      const float dz = co[(size_t)rI * 3 + 2] - co[(size_t)cI * 3 + 2];
      f32x4 c4;
      c4[0] = dx; c4[1] = dy; c4[2] = dz; c4[3] = dx * dx + dy * dy + dz * dz;
      *reinterpret_cast<f32x4*>(&cdw[lane * 4]) = c4;
    }
    // --- 3. stage gA[r]+gB[c] (f32 add, bf16 store) ---
#pragma unroll
    for (int rr = 0; rr < 4; ++rr) {
      const int el = rr * 8 + (lane >> 3), ch = lane & 7;
      const int rI = idxw[el], cI = idxw[32 + el];
      const uint4 va = *reinterpret_cast<const uint4*>(gA + (size_t)rI * 64 + ch * 8);
      const uint4 vb = *reinterpret_cast<const uint4*>(gB + (size_t)cI * 64 + ch * 8);
      uint4 o;
      {
        const unsigned int a[4] = {va.x, va.y, va.z, va.w};
        const unsigned int b[4] = {vb.x, vb.y, vb.z, vb.w};
        unsigned int r[4];
#pragma unroll
        for (int q = 0; q < 4; ++q) {
          const float s0 = lo_bf(a[q]) + lo_bf(b[q]);
          const float s1 = hi_bf(a[q]) + hi_bf(b[q]);
          r[q] = ((unsigned int)f2bf(s1) << 16) | (unsigned int)f2bf(s0);
        }
        o.x = r[0]; o.y = r[1]; o.z = r[2]; o.w = r[3];
      }
      *reinterpret_cast<uint4*>(&xw[el * 72 + ch * 8]) = o;
    }
    // --- 4. C-init: acc = staged sum + bSum ---
    f32x4 acc[2][4];
#pragma unroll
    for (int mt = 0; mt < 2; ++mt)
#pragma unroll
      for (int nt = 0; nt < 4; ++nt)
#pragma unroll
        for (int j = 0; j < 4; ++j) {
          const int row = g * 4 + j + 16 * mt, col = t + 16 * nt;
          acc[mt][nt][j] = bf2f(xw[row * 72 + col]) + bS_r[nt];
        }
    // --- 5. layer-1 MFMA (ea + radial part), K=32 ---
#pragma unroll
    for (int mt = 0; mt < 2; ++mt) {
      short8 a = {};
      const int er = t + 16 * mt;
      long eg = e0 + er;
      if (eg >= E) eg = E - 1;
      if (g < 2) {
        const float* pe = ea + (size_t)eg * 16 + g * 8;
        const f32x4 x0 = *reinterpret_cast<const f32x4*>(pe);
        const f32x4 x1 = *reinterpret_cast<const f32x4*>(pe + 4);
#pragma unroll
        for (int q = 0; q < 4; ++q) {
          a[q] = (short)f2bf(x0[q]);
          a[4 + q] = (short)f2bf(x1[q]);
        }
      } else if (g == 2) {
        a[0] = (short)f2bf(cdw[er * 4 + 3]);
      }
#pragma unroll
      for (int nt = 0; nt < 4; ++nt) {
        const short8 b = *reinterpret_cast<const short8*>(&S.Bea[(t + 16 * nt) * 40 + g * 8]);
        acc[mt][nt] = __builtin_amdgcn_mfma_f32_16x16x32_bf16(a, b, acc[mt][nt], 0, 0, 0);
      }
    }
    // relu -> t1 (bf16 back to x)
#pragma unroll
    for (int mt = 0; mt < 2; ++mt)
#pragma unroll
      for (int nt = 0; nt < 4; ++nt)
#pragma unroll
        for (int j = 0; j < 4; ++j) {
          const float v = fmaxf(acc[mt][nt][j], 0.f);
          xw[(g * 4 + j + 16 * mt) * 72 + t + 16 * nt] = f2bf(v);
        }
    // --- 6. layer-2 MFMA: m = relu(t1 @ We2 + be2) ---
    short8 A2[2][2];
#pragma unroll
    for (int mt = 0; mt < 2; ++mt)
#pragma unroll
      for (int kt = 0; kt < 2; ++kt)
        A2[mt][kt] = *reinterpret_cast<const short8*>(&xw[(t + 16 * mt) * 72 + kt * 32 + g * 8]);
    f32x4 m2[2][4];
#pragma unroll
    for (int mt = 0; mt < 2; ++mt)
#pragma unroll
      for (int nt = 0; nt < 4; ++nt) {
        f32x4 c;
        c[0] = be2_r[nt]; c[1] = be2_r[nt]; c[2] = be2_r[nt]; c[3] = be2_r[nt];
#pragma unroll
        for (int kt = 0; kt < 2; ++kt)
          c = __builtin_amdgcn_mfma_f32_16x16x32_bf16(A2[mt][kt], fWe2[nt][kt], c, 0, 0, 0);
#pragma unroll
        for (int j = 0; j < 4; ++j) c[j] = fmaxf(c[j], 0.f);
        m2[mt][nt] = c;
      }
    // write m (bf16) for coord-MLP A-operand
#pragma unroll
    for (int mt = 0; mt < 2; ++mt)
#pragma unroll
      for (int nt = 0; nt < 4; ++nt)
#pragma unroll
        for (int j = 0; j < 4; ++j)
          xw[(g * 4 + j + 16 * mt) * 72 + t + 16 * nt] = f2bf(m2[mt][nt][j]);
    // --- 7. agg_m atomics ---
#pragma unroll
    for (int mt = 0; mt < 2; ++mt)
#pragma unroll
      for (int j = 0; j < 4; ++j) {
        const int row = g * 4 + j + 16 * mt;
        const long eg = e0 + row;
        if (eg < E) {
          const int rI = idxw[row];
          float* base = agg_m + (size_t)rI * 64 + t;
#pragma unroll
          for (int nt = 0; nt < 4; ++nt) atomAddF(base + 16 * nt, m2[mt][nt][j]);
        }
      }
    // --- 8. coord MLP MFMA: p = relu(m @ Wc1 + bc1) ---
    short8 A3[2][2];
#pragma unroll
    for (int mt = 0; mt < 2; ++mt)
#pragma unroll
      for (int kt = 0; kt < 2; ++kt)
        A3[mt][kt] = *reinterpret_cast<const short8*>(&xw[(t + 16 * mt) * 72 + kt * 32 + g * 8]);
    f32x4 p[2][4];
#pragma unroll
    for (int mt = 0; mt < 2; ++mt)
#pragma unroll
      for (int nt = 0; nt < 4; ++nt) {
        f32x4 c;
        c[0] = bc1_r[nt]; c[1] = bc1_r[nt]; c[2] = bc1_r[nt]; c[3] = bc1_r[nt];
#pragma unroll
        for (int kt = 0; kt < 2; ++kt) {
          const short8 b = *reinterpret_cast<const short8*>(
              &S.Wc1t[(t + 16 * nt) * 72 + kt * 32 + g * 8]);
          c = __builtin_amdgcn_mfma_f32_16x16x32_bf16(A3[mt][kt], b, c, 0, 0, 0);
        }
#pragma unroll
        for (int j = 0; j < 4; ++j) c[j] = fmaxf(c[j], 0.f);
        p[mt][nt] = c;
      }
    // --- 9. s = p . Wc2 + bc2 (reduce over 64 cols) ---
    float sv[2][4];
#pragma unroll
    for (int mt = 0; mt < 2; ++mt)
#pragma unroll
      for (int j = 0; j < 4; ++j) {
        float ps = 0.f;
#pragma unroll
        for (int nt = 0; nt < 4; ++nt) ps = fmaf(p[mt][nt][j], wc2_r[nt], ps);
        sv[mt][j] = ps;
      }
#pragma unroll
    for (int d = 1; d < 16; d <<= 1)
#pragma unroll
      for (int mt = 0; mt < 2; ++mt)
#pragma unroll
        for (int j = 0; j < 4; ++j) sv[mt][j] += __shfl_xor(sv[mt][j], d, 64);
#pragma unroll
    for (int mt = 0; mt < 2; ++mt)
#pragma unroll
      for (int j = 0; j < 4; ++j) sv[mt][j] += bc2v;
    // --- 10. agg_x + cnt atomics ---
    if (t < 3) {
#pragma unroll
      for (int mt = 0; mt < 2; ++mt)
#pragma unroll
        for (int j = 0; j < 4; ++j) {
          const int row = g * 4 + j + 16 * mt;
          const long eg = e0 + row;
          if (eg < E) {
            const int rI = idxw[row];
            atomAddF(agg_x + (size_t)rI * 3 + t, cdw[row * 4 + t] * sv[mt][j]);
          }
        }
    } else if (t == 3) {
#pragma unroll
      for (int mt = 0; mt < 2; ++mt)
#pragma unroll
        for (int j = 0; j < 4; ++j) {
          const int row = g * 4 + j + 16 * mt;
          const long eg = e0 + row;
          if (eg < E) atomAddF(cnt + idxw[row], 1.0f);
        }
    }
  }
}

// ---------------- k_node: node MLP + output + coord update ---------------
__global__ __launch_bounds__(256) void k_node(
    const float* __restrict__ h, const float* __restrict__ agg_m,
    const float* __restrict__ agg_x, const float* __restrict__ cnt,
    const float* __restrict__ co,
    const float* __restrict__ Wn1, const float* __restrict__ bn1,
    const float* __restrict__ Wn2, const float* __restrict__ bn2,
    const float* __restrict__ Wo, const float* __restrict__ bo,
    float* __restrict__ out, float* __restrict__ co_out, int N) {
  __shared__ float Wn1s[128 * 64];
  __shared__ float Wn2s[64 * 64];
  __shared__ float Wos[64 * 64];
  __shared__ float bn1s[64], bn2s[64], bos[64];
  __shared__ float xls[4][136];

  for (int i = threadIdx.x; i < 128 * 64; i += 256) Wn1s[i] = Wn1[i];
  for (int i = threadIdx.x; i < 64 * 64; i += 256) {
    Wn2s[i] = Wn2[i];
    Wos[i] = Wo[i];
  }
  if (threadIdx.x < 64) {
    bn1s[threadIdx.x] = bn1[threadIdx.x];
    bn2s[threadIdx.x] = bn2[threadIdx.x];
    bos[threadIdx.x] = bo[threadIdx.x];
  }
  __syncthreads();

  const int wave = threadIdx.x >> 6, lane = threadIdx.x & 63;
  float* xw = xls[wave];
  const int nwaves = gridDim.x * 4;

  for (int n = blockIdx.x * 4 + wave; n < N; n += nwaves) {
    xw[lane] = h[(size_t)n * 64 + lane];
    xw[64 + lane] = agg_m[(size_t)n * 64 + lane];

    float a = bn1s[lane];
    for (int kk = 0; kk < 32; ++kk) {
      const float4 xv = *reinterpret_cast<const float4*>(&xw[kk * 4]);
      a = fmaf(xv.x, Wn1s[(kk * 4 + 0) * 64 + lane], a);
      a = fmaf(xv.y, Wn1s[(kk * 4 + 1) * 64 + lane], a);
      a = fmaf(xv.z, Wn1s[(kk * 4 + 2) * 64 + lane], a);
      a = fmaf(xv.w, Wn1s[(kk * 4 + 3) * 64 + lane], a);
    }
    a = fmaxf(a, 0.0f);
    xw[lane] = a;

    float a2 = bn2s[lane];
    for (int kk = 0; kk < 16; ++kk) {
      const float4 xv = *reinterpret_cast<const float4*>(&xw[kk * 4]);
      a2 = fmaf(xv.x, Wn2s[(kk * 4 + 0) * 64 + lane], a2);
      a2 = fmaf(xv.y, Wn2s[(kk * 4 + 1) * 64 + lane], a2);
      a2 = fmaf(xv.z, Wn2s[(kk * 4 + 2) * 64 + lane], a2);
      a2 = fmaf(xv.w, Wn2s[(kk * 4 + 3) * 64 + lane], a2);
    }
    xw[64 + lane] = a2;

    float a3 = bos[lane];
    for (int kk = 0; kk < 16; ++kk) {
      const float4 xv = *reinterpret_cast<const float4*>(&xw[64 + kk * 4]);
      a3 = fmaf(xv.x, Wos[(kk * 4 + 0) * 64 + lane], a3);
      a3 = fmaf(xv.y, Wos[(kk * 4 + 1) * 64 + lane], a3);
      a3 = fmaf(xv.z, Wos[(kk * 4 + 2) * 64 + lane], a3);
      a3 = fmaf(xv.w, Wos[(kk * 4 + 3) * 64 + lane], a3);
    }
    out[(size_t)n * 64 + lane] = a3;

    if (lane < 3)
      co_out[(size_t)n * 3 + lane] =
          co[(size_t)n * 3 + lane] + agg_x[(size_t)n * 3 + lane] / fmaxf(cnt[n], 1.0f);
  }
}

extern "C" void kernel_launch(void* const* d_in, const int* in_sizes, int n_in,
                              void* d_out, int out_size, void* d_ws, size_t ws_size,
                              hipStream_t stream) {
  const float* nf = (const float*)d_in[0];
  const float* ea = (const float*)d_in[1];
  const float* co = (const float*)d_in[2];
  const int* ei = (const int*)d_in[3];
  const float* W_in = (const float*)d_in[4];
  const float* b_in = (const float*)d_in[5];
  const float* W_out = (const float*)d_in[6];
  const float* b_out = (const float*)d_in[7];
  const float* We1 = (const float*)d_in[8];
  const float* be1 = (const float*)d_in[9];
  const float* We2 = (const float*)d_in[10];
  const float* be2 = (const float*)d_in[11];
  const float* Wn1 = (const float*)d_in[12];
  const float* bn1 = (const float*)d_in[13];
  const float* Wn2 = (const float*)d_in[14];
  const float* bn2 = (const float*)d_in[15];
  const float* Wc1 = (const float*)d_in[16];
  const float* bc1 = (const float*)d_in[17];
  const float* Wc2 = (const float*)d_in[18];
  const float* bc2 = (const float*)d_in[19];

  const int N = in_sizes[0] / 32;
  const int E = in_sizes[1] / 16;

  float* ws = (float*)d_ws;
  float* h = ws;
  float* agg_m = ws + (size_t)N * 64;
  float* agg_x = agg_m + (size_t)N * 64;
  float* cntb = agg_x + (size_t)N * 3;
  float* WA = cntb + N;
  float* WB = WA + 2048;
  float* bSum = WB + 2048;

  float* outp = (float*)d_out;
  float* co_out = outp + (size_t)N * 64;
  unsigned short* gA = (unsigned short*)d_out;           // N*64 bf16
  unsigned short* gB = gA + (size_t)N * 64;              // N*64 bf16

  hipMemsetAsync(agg_m, 0, (size_t)N * 68 * sizeof(float), stream);

  k_fold<<<1, 256, 0, stream>>>(W_in, b_in, We1, be1, WA, WB, bSum);
  k_embed<<<2048, 256, 0, stream>>>(nf, W_in, b_in, WA, WB, h, gA, gB, N);
  k_edge<<<2048, 256, 0, stream>>>(gA, gB, ea, co, ei, We1, bSum, be2, We2,
                                   bc1, Wc1, Wc2, bc2, agg_m, agg_x, cntb, E);
  k_node<<<2048, 256, 0, stream>>>(h, agg_m, agg_x, cntb, co, Wn1, bn1, Wn2,
                                   bn2, W_out, b_out, outp, co_out, N);
}